// Round 2
// baseline (1373.968 us; speedup 1.0000x reference)
//
#include <hip/hip_runtime.h>

// Problem constants (fixed by reference):
#define F_DIM  4096
#define NROUNDS 12
#define NBLK_  2048
#define GM     8192   // B*S
#define GN     4096   // F_OUT
#define GK     4096   // F_IN
#define KITERS (GK / 32)

typedef short short8 __attribute__((ext_vector_type(8)));
typedef float f32x4  __attribute__((ext_vector_type(4)));
typedef unsigned short us8 __attribute__((ext_vector_type(8)));
typedef unsigned short ushortT;

typedef __attribute__((address_space(3))) void lds_void;
typedef const __attribute__((address_space(1))) void glob_void;

// ---- ordered-uint encoding for float atomics (monotone map float -> uint) ----
__device__ __forceinline__ unsigned ordf(float f) {
    unsigned u = __float_as_uint(f);
    return (u & 0x80000000u) ? ~u : (u | 0x80000000u);
}
__device__ __forceinline__ float unordf(unsigned u) {
    unsigned v = (u & 0x80000000u) ? (u & 0x7fffffffu) : ~u;
    return __uint_as_float(v);
}
// RNE float -> bf16 bits (no NaN/inf in this problem)
__device__ __forceinline__ ushortT f2bf(float f) {
    unsigned u = __float_as_uint(f);
    return (ushortT)((u + 0x7fffu + ((u >> 16) & 1u)) >> 16);
}

__global__ void init_mm_kernel(unsigned* mm) {
    // mm[0]=xmin, mm[1]=xmax, mm[2]=wmin, mm[3]=wmax (ordered-uint)
    if (threadIdx.x < 4) mm[threadIdx.x] = (threadIdx.x & 1) ? 0u : 0xFFFFFFFFu;
}

// Rotate R rows per block through 12 permute+2x2 rounds in LDS (in-place),
// reduce global min/max (fp32, pre-bf16 -> exact lo/hi), store rotated bf16.
// R=2: 32 KB LDS -> 5 blocks/CU for latency hiding; 2 barriers per round.
template <int R>
__global__ __launch_bounds__(256)
void rotate_store_kernel(const float* __restrict__ src,
                         const int*   __restrict__ perms,
                         const float* __restrict__ mats,
                         unsigned*    __restrict__ mm,
                         ushortT*     __restrict__ dst)
{
    __shared__ alignas(16) float buf[R][F_DIM];
    const int t = threadIdx.x;
    const size_t r0 = (size_t)blockIdx.x * R;

    #pragma unroll
    for (int i = 0; i < R; ++i) {
        const float4* s4 = (const float4*)(src + (r0 + i) * F_DIM);
        #pragma unroll
        for (int q = 0; q < 4; ++q)
            ((float4*)buf[i])[t + q * 256] = s4[t + q * 256];
    }
    __syncthreads();

    #pragma unroll 1
    for (int r = 0; r < NROUNDS; ++r) {
        // round metadata into registers: thread t owns 2x2-blocks t+q*256
        int2   p[8];
        float4 mt[8];
        const int2*   pr = (const int2*)(perms + (size_t)r * F_DIM);
        const float4* mr = (const float4*)(mats + (size_t)r * NBLK_ * 4);
        #pragma unroll
        for (int q = 0; q < 8; ++q) { int k = t + q * 256; p[q] = pr[k]; mt[q] = mr[k]; }

        // gather phase (all rows), one barrier, write phase, one barrier
        float2 v[R][8];
        #pragma unroll
        for (int i = 0; i < R; ++i)
            #pragma unroll
            for (int q = 0; q < 8; ++q)
                v[i][q] = make_float2(buf[i][p[q].x], buf[i][p[q].y]);
        __syncthreads();
        #pragma unroll
        for (int i = 0; i < R; ++i)
            #pragma unroll
            for (int q = 0; q < 8; ++q) {
                int k = t + q * 256;
                ((float2*)buf[i])[k] =
                    make_float2(mt[q].x * v[i][q].x + mt[q].y * v[i][q].y,
                                mt[q].z * v[i][q].x + mt[q].w * v[i][q].y);
            }
        __syncthreads();
    }

    // fp32 min/max (matches reference binning range) + bf16 store
    float lmin = __FLT_MAX__, lmax = -__FLT_MAX__;
    #pragma unroll
    for (int i = 0; i < R; ++i) {
        ushortT* drow = dst + (r0 + i) * F_DIM;
        #pragma unroll
        for (int q = 0; q < 2; ++q) {
            const int e = t + q * 256;   // us8 chunk id in [0,512)
            float4 v0 = ((const float4*)buf[i])[e * 2 + 0];
            float4 v1 = ((const float4*)buf[i])[e * 2 + 1];
            float vv[8] = {v0.x, v0.y, v0.z, v0.w, v1.x, v1.y, v1.z, v1.w};
            us8 pk;
            #pragma unroll
            for (int j = 0; j < 8; ++j) {
                lmin = fminf(lmin, vv[j]);
                lmax = fmaxf(lmax, vv[j]);
                pk[j] = f2bf(vv[j]);
            }
            *(us8*)(drow + e * 8) = pk;
        }
    }
    #pragma unroll
    for (int off = 32; off > 0; off >>= 1) {
        lmin = fminf(lmin, __shfl_down(lmin, off));
        lmax = fmaxf(lmax, __shfl_down(lmax, off));
    }
    if ((t & 63) == 0) {
        atomicMin(&mm[0], ordf(lmin));
        atomicMax(&mm[1], ordf(lmax));
    }
}

// In-place quant-dequant of rotated bf16 (x then w contiguous in ws).
__global__ __launch_bounds__(256)
void quant_kernel(ushortT* __restrict__ data, const unsigned* __restrict__ mm,
                  unsigned nx_chunks)
{
    const unsigned i = blockIdx.x * 256 + threadIdx.x;  // us8 chunk index
    const int sel = (i < nx_chunks) ? 0 : 2;
    const float lo = unordf(mm[sel]);
    const float hi = unordf(mm[sel + 1]);
    const float scale = (hi - lo) * (1.0f / 255.0f);
    const float inv   = 255.0f / (hi - lo);
    us8 c = *(const us8*)(data + (size_t)i * 8);
    us8 o;
    #pragma unroll
    for (int j = 0; j < 8; ++j) {
        float f = __uint_as_float((unsigned)(unsigned short)c[j] << 16);
        float q = fminf(fmaxf(rintf((f - lo) * inv), 0.0f), 255.0f);
        o[j] = f2bf(q * scale + lo);
    }
    *(us8*)(data + (size_t)i * 8) = o;
}

// C = A(MxK,bf16) * B(NxK,bf16)^T + bias, fp32 out. 128x128 tile, BK=32,
// DOUBLE-BUFFERED LDS: prefetch tile k+1 right after the barrier, compute
// tile k -> the vmcnt(0) drain at the next barrier overlaps with compute.
__global__ __launch_bounds__(256)
void gemm_bias_kernel(const ushortT* __restrict__ A,
                      const ushortT* __restrict__ B,
                      const float*   __restrict__ bias,
                      float*         __restrict__ C)
{
    __shared__ alignas(16) ushortT As[2][128 * 32];  // 2 x 8 KB
    __shared__ alignas(16) ushortT Bs[2][128 * 32];  // 2 x 8 KB
    const int t = threadIdx.x;
    const int mb = blockIdx.x, nb = blockIdx.y;
    const int lane = t & 63, wv = t >> 6;
    const int wm = (wv & 1) * 64, wn = (wv >> 1) * 64;
    const int rr = lane & 15, kc = lane >> 4;

    // staging: slot s in [0,512): row = s&127, kchunk = s>>7 (8 bf16 each)
    const int s0 = t, s1 = 256 + t;
    const ushortT* ga0 = A + ((size_t)(mb * 128 + (s0 & 127)) * GK + (s0 >> 7) * 8);
    const ushortT* ga1 = A + ((size_t)(mb * 128 + (s1 & 127)) * GK + (s1 >> 7) * 8);
    const ushortT* gb0 = B + ((size_t)(nb * 128 + (s0 & 127)) * GK + (s0 >> 7) * 8);
    const ushortT* gb1 = B + ((size_t)(nb * 128 + (s1 & 127)) * GK + (s1 >> 7) * 8);

    f32x4 acc[4][4];
    const f32x4 zz = {0.f, 0.f, 0.f, 0.f};
    #pragma unroll
    for (int mi = 0; mi < 4; ++mi)
        #pragma unroll
        for (int ni = 0; ni < 4; ++ni)
            acc[mi][ni] = zz;

    auto stage = [&](int bi, int ko) {
        __builtin_amdgcn_global_load_lds((glob_void*)(ga0 + ko),
            (lds_void*)&As[bi][(wv * 64) * 8], 16, 0, 0);
        __builtin_amdgcn_global_load_lds((glob_void*)(ga1 + ko),
            (lds_void*)&As[bi][(256 + wv * 64) * 8], 16, 0, 0);
        __builtin_amdgcn_global_load_lds((glob_void*)(gb0 + ko),
            (lds_void*)&Bs[bi][(wv * 64) * 8], 16, 0, 0);
        __builtin_amdgcn_global_load_lds((glob_void*)(gb1 + ko),
            (lds_void*)&Bs[bi][(256 + wv * 64) * 8], 16, 0, 0);
    };
    auto compute = [&](int bi) {
        short8 af[4], bfr[4];
        #pragma unroll
        for (int mi = 0; mi < 4; ++mi)
            af[mi] = *(const short8*)&As[bi][(kc * 128 + wm + mi * 16 + rr) * 8];
        #pragma unroll
        for (int ni = 0; ni < 4; ++ni)
            bfr[ni] = *(const short8*)&Bs[bi][(kc * 128 + wn + ni * 16 + rr) * 8];
        #pragma unroll
        for (int mi = 0; mi < 4; ++mi)
            #pragma unroll
            for (int ni = 0; ni < 4; ++ni)
                acc[mi][ni] = __builtin_amdgcn_mfma_f32_16x16x32_bf16(
                    af[mi], bfr[ni], acc[mi][ni], 0, 0, 0);
    };

    stage(0, 0);
    #pragma unroll 1
    for (int it = 0; it < KITERS - 1; ++it) {
        __syncthreads();                      // buf[it&1] staged & prior reads done
        stage((it + 1) & 1, (it + 1) * 32);   // prefetch next tile (other buffer)
        compute(it & 1);                      // overlaps with prefetch in flight
    }
    __syncthreads();
    compute((KITERS - 1) & 1);

    float bv[4];
    #pragma unroll
    for (int ni = 0; ni < 4; ++ni)
        bv[ni] = bias[nb * 128 + wn + ni * 16 + rr];

    // C/D layout: row-in-16 = kc*4 + reg, col-in-16 = rr
    #pragma unroll
    for (int mi = 0; mi < 4; ++mi) {
        #pragma unroll
        for (int ni = 0; ni < 4; ++ni) {
            const int col = nb * 128 + wn + ni * 16 + rr;
            #pragma unroll
            for (int r = 0; r < 4; ++r) {
                const int row = mb * 128 + wm + mi * 16 + kc * 4 + r;
                C[(size_t)row * GN + col] = acc[mi][ni][r] + bv[ni];
            }
        }
    }
}

extern "C" void kernel_launch(void* const* d_in, const int* in_sizes, int n_in,
                              void* d_out, int out_size, void* d_ws, size_t ws_size,
                              hipStream_t stream)
{
    (void)in_sizes; (void)n_in; (void)out_size; (void)ws_size;
    const float* x     = (const float*)d_in[0];
    const float* w     = (const float*)d_in[1];
    const float* bias  = (const float*)d_in[2];
    const float* mats  = (const float*)d_in[3];
    const int*   perms = (const int*)d_in[4];
    float* out = (float*)d_out;

    char* ws = (char*)d_ws;
    ushortT*  xq = (ushortT*)ws;                                    // 64 MiB (rot -> quant in-place)
    ushortT*  wq = (ushortT*)(ws + (size_t)GM * GK * 2);            // 32 MiB
    unsigned* mm = (unsigned*)(ws + (size_t)GM * GK * 2 + (size_t)GN * GK * 2);

    init_mm_kernel<<<1, 64, 0, stream>>>(mm);
    // single rotation pass: rotate + min/max + store rotated bf16
    rotate_store_kernel<2><<<GM / 2, 256, 0, stream>>>(x, perms, mats, mm + 0, xq);
    rotate_store_kernel<2><<<GN / 2, 256, 0, stream>>>(w, perms, mats, mm + 2, wq);
    // in-place quant-dequant of both operands (x chunks then w chunks)
    quant_kernel<<<(GM + GN) * (GK / 8) / 256, 256, 0, stream>>>(
        xq, mm, (unsigned)((size_t)GM * GK / 8));
    // GEMM + bias
    gemm_bias_kernel<<<dim3(GM / 128, GN / 128), 256, 0, stream>>>(xq, wq, bias, out);
}

// Round 4
// 877.847 us; speedup vs baseline: 1.5652x; 1.5652x over previous
//
#include <hip/hip_runtime.h>

// Problem constants (fixed by reference):
#define F_DIM  4096
#define NROUNDS 12
#define GM     8192   // B*S
#define GN     4096   // F_OUT
#define GK     4096   // F_IN
#define BK     64
#define NIT    (GK / BK)   // 64

typedef short short8 __attribute__((ext_vector_type(8)));
typedef float f32x4  __attribute__((ext_vector_type(4)));
typedef unsigned short us8 __attribute__((ext_vector_type(8)));
typedef unsigned short ushortT;

typedef __attribute__((address_space(3))) void lds_void;
typedef const __attribute__((address_space(1))) void glob_void;

__device__ __forceinline__ unsigned ordf(float f) {
    unsigned u = __float_as_uint(f);
    return (u & 0x80000000u) ? ~u : (u | 0x80000000u);
}
__device__ __forceinline__ float unordf(unsigned u) {
    unsigned v = (u & 0x80000000u) ? (u & 0x7fffffffu) : ~u;
    return __uint_as_float(v);
}
__device__ __forceinline__ unsigned f2bf(float f) {  // RNE float->bf16 bits
    unsigned u = __float_as_uint(f);
    return ((u + 0x7fffu + ((u >> 16) & 1u)) >> 16) & 0xffffu;
}

__global__ void init_mm_kernel(unsigned* mm) {
    if (threadIdx.x < 4) mm[threadIdx.x] = (threadIdx.x & 1) ? 0u : 0xFFFFFFFFu;
}

// ---------------------------------------------------------------------------
// Rotation: 4 rows/block, FEATURE-MAJOR LDS. buf[sig(f)] = float4 of rows 0..3
// at feature f, sig(f) = (f>>1) + (f&1)*2048. One ds_read_b128 gathers 4 rows.
// Metadata prefetched one round ahead. NOTE: mats = 2048 float4 PER ROUND
// (8192 floats), perms = 2048 int2 per round (R3 bug: used F_DIM=4096 floats).
// Output: exact fp32 stored as hi16 plane (dst_hi, later quantized in place
// to bf16) + lo16 plane (dst_lo, scratch in d_out).
// ---------------------------------------------------------------------------
__global__ __launch_bounds__(256)
void rotate_store_kernel(const float* __restrict__ src,
                         const int*   __restrict__ perms,
                         const float* __restrict__ mats,
                         unsigned*    __restrict__ mm,
                         ushortT*     __restrict__ dst_hi,
                         ushortT*     __restrict__ dst_lo)
{
    __shared__ float4 buf[F_DIM];   // 64 KB
    const int t = threadIdx.x;
    const size_t r0 = (size_t)blockIdx.x * 4;
    const int2*   pbase = (const int2*)perms;    // 2048 int2 per round
    const float4* mbase = (const float4*)mats;   // 2048 float4 per round

    const float2* s0 = (const float2*)(src + (r0 + 0) * F_DIM);
    const float2* s1 = (const float2*)(src + (r0 + 1) * F_DIM);
    const float2* s2 = (const float2*)(src + (r0 + 2) * F_DIM);
    const float2* s3 = (const float2*)(src + (r0 + 3) * F_DIM);
    #pragma unroll
    for (int q = 0; q < 8; ++q) {
        const int e = t + q * 256;
        float2 a = s0[e], b = s1[e], c = s2[e], d = s3[e];
        buf[e]        = make_float4(a.x, b.x, c.x, d.x);
        buf[e + 2048] = make_float4(a.y, b.y, c.y, d.y);
    }
    __syncthreads();

    int2 pA[8], pB[8];
    float4 mA[8], mB[8];
    #pragma unroll
    for (int q = 0; q < 8; ++q) { int k = t + q * 256; pA[q] = pbase[k]; mA[q] = mbase[k]; }

    #pragma unroll 1
    for (int r = 0; r < NROUNDS; r += 2) {
        // ---- round r (meta in pA/mA), prefetch r+1 into pB/mB ----
        float4 va[8], vb[8];
        #pragma unroll
        for (int q = 0; q < 8; ++q) {
            int fa = pA[q].x, fb = pA[q].y;
            va[q] = buf[(fa >> 1) + ((fa & 1) << 11)];
            vb[q] = buf[(fb >> 1) + ((fb & 1) << 11)];
        }
        {
            const int2*   pr = pbase + (size_t)(r + 1) * 2048;
            const float4* mr = mbase + (size_t)(r + 1) * 2048;
            #pragma unroll
            for (int q = 0; q < 8; ++q) { int k = t + q * 256; pB[q] = pr[k]; mB[q] = mr[k]; }
        }
        __syncthreads();
        #pragma unroll
        for (int q = 0; q < 8; ++q) {
            const int k = t + q * 256;
            float4 A = va[q], B = vb[q], M = mA[q];
            buf[k]        = make_float4(M.x*A.x + M.y*B.x, M.x*A.y + M.y*B.y,
                                        M.x*A.z + M.y*B.z, M.x*A.w + M.y*B.w);
            buf[k + 2048] = make_float4(M.z*A.x + M.w*B.x, M.z*A.y + M.w*B.y,
                                        M.z*A.z + M.w*B.z, M.z*A.w + M.w*B.w);
        }
        __syncthreads();

        // ---- round r+1 (meta in pB/mB), prefetch r+2 into pA/mA ----
        #pragma unroll
        for (int q = 0; q < 8; ++q) {
            int fa = pB[q].x, fb = pB[q].y;
            va[q] = buf[(fa >> 1) + ((fa & 1) << 11)];
            vb[q] = buf[(fb >> 1) + ((fb & 1) << 11)];
        }
        if (r + 2 < NROUNDS) {
            const int2*   pr = pbase + (size_t)(r + 2) * 2048;
            const float4* mr = mbase + (size_t)(r + 2) * 2048;
            #pragma unroll
            for (int q = 0; q < 8; ++q) { int k = t + q * 256; pA[q] = pr[k]; mA[q] = mr[k]; }
        }
        __syncthreads();
        #pragma unroll
        for (int q = 0; q < 8; ++q) {
            const int k = t + q * 256;
            float4 A = va[q], B = vb[q], M = mB[q];
            buf[k]        = make_float4(M.x*A.x + M.y*B.x, M.x*A.y + M.y*B.y,
                                        M.x*A.z + M.y*B.z, M.x*A.w + M.y*B.w);
            buf[k + 2048] = make_float4(M.z*A.x + M.w*B.x, M.z*A.y + M.w*B.y,
                                        M.z*A.z + M.w*B.z, M.z*A.w + M.w*B.w);
        }
        __syncthreads();
    }

    // exact fp32 min/max + split store: hi16 plane (future bf16 operand slot)
    // and lo16 plane (scratch) -> quant kernel reconstructs exact fp32.
    float lmin = __FLT_MAX__, lmax = -__FLT_MAX__;
    #pragma unroll
    for (int q = 0; q < 8; ++q) {
        const int e = t + q * 256;
        float4 f0 = buf[e];          // feature 2e,   rows 0..3
        float4 f1 = buf[e + 2048];   // feature 2e+1, rows 0..3
        lmin = fminf(lmin, fminf(fminf(f0.x, f0.y), fminf(f0.z, f0.w)));
        lmin = fminf(lmin, fminf(fminf(f1.x, f1.y), fminf(f1.z, f1.w)));
        lmax = fmaxf(lmax, fmaxf(fmaxf(f0.x, f0.y), fmaxf(f0.z, f0.w)));
        lmax = fmaxf(lmax, fmaxf(fmaxf(f1.x, f1.y), fmaxf(f1.z, f1.w)));
        const float vr[4][2] = {{f0.x, f1.x}, {f0.y, f1.y}, {f0.z, f1.z}, {f0.w, f1.w}};
        #pragma unroll
        for (int i = 0; i < 4; ++i) {
            unsigned u0 = __float_as_uint(vr[i][0]);
            unsigned u1 = __float_as_uint(vr[i][1]);
            ((unsigned*)(dst_hi + (r0 + i) * F_DIM))[e] = (u0 >> 16) | (u1 & 0xffff0000u);
            ((unsigned*)(dst_lo + (r0 + i) * F_DIM))[e] = (u0 & 0xffffu) | (u1 << 16);
        }
    }
    #pragma unroll
    for (int off = 32; off > 0; off >>= 1) {
        lmin = fminf(lmin, __shfl_down(lmin, off));
        lmax = fmaxf(lmax, __shfl_down(lmax, off));
    }
    if ((t & 63) == 0) {
        atomicMin(&mm[0], ordf(lmin));
        atomicMax(&mm[1], ordf(lmax));
    }
}

// Quant-dequant from EXACT fp32 (hi|lo planes); writes RNE bf16 over hi plane.
__global__ __launch_bounds__(256)
void quant_kernel(ushortT* __restrict__ hi, const ushortT* __restrict__ lo,
                  const unsigned* __restrict__ mm, unsigned nx_chunks)
{
    const unsigned i = blockIdx.x * 256 + threadIdx.x;  // us8 chunk index
    const int sel = (i < nx_chunks) ? 0 : 2;
    const float lov = unordf(mm[sel]);
    const float hiv = unordf(mm[sel + 1]);
    const float scale = (hiv - lov) / 255.0f;   // IEEE div, matches reference
    us8 h = *(const us8*)(hi + (size_t)i * 8);
    us8 l = *(const us8*)(lo + (size_t)i * 8);
    us8 o;
    #pragma unroll
    for (int j = 0; j < 8; ++j) {
        float f = __uint_as_float(((unsigned)h[j] << 16) | (unsigned)l[j]);
        float q = rintf((f - lov) / scale);     // IEEE div + RNE = jnp.round
        q = fminf(fmaxf(q, 0.0f), 255.0f);
        o[j] = (ushortT)f2bf(q * scale + lov);
    }
    *(us8*)(hi + (size_t)i * 8) = o;
}

// ---------------------------------------------------------------------------
// GEMM: C = A(MxK) * B(NxK)^T + bias. 128x128 tile, BK=64, single LDS buffer.
// Coalesced staging (one row's BK slice = 128 B = 1 cache line, 8 lanes/row),
// XOR bank swizzle on the global side. 3-barrier loop: frag reads -> barrier
// -> restage next tile -> 32 MFMAs. 1-D supertile swizzle for L2 locality.
// ---------------------------------------------------------------------------
__global__ __launch_bounds__(256)
void gemm_bias_kernel(const ushortT* __restrict__ A,
                      const ushortT* __restrict__ B,
                      const float*   __restrict__ bias,
                      float*         __restrict__ C)
{
    __shared__ alignas(16) ushortT As[128 * 8 * 8];  // 16 KB: slot = row*8 + c_lds
    __shared__ alignas(16) ushortT Bs[128 * 8 * 8];  // 16 KB
    const int t = threadIdx.x;
    // supertile: 8 consecutive mb x 32 nb per 256-block group
    const int bid = blockIdx.x;
    const int mb = (bid >> 8) * 8 + (bid & 7);
    const int nb = (bid >> 3) & 31;
    const int lane = t & 63, wv = t >> 6;
    const int wm = (wv & 1) * 64, wn = (wv >> 1) * 64;
    const int rr = lane & 15, kc = lane >> 4;

    const int srow = t >> 3;                     // row within 32-row group
    const int cg   = (t & 7) ^ (srow & 7);       // global chunk (swizzled)
    const ushortT* pa = A + ((size_t)(mb * 128 + srow) * GK) + cg * 8;
    const ushortT* pb = B + ((size_t)(nb * 128 + srow) * GK) + cg * 8;

    f32x4 acc[4][4];
    const f32x4 zz = {0.f, 0.f, 0.f, 0.f};
    #pragma unroll
    for (int mi = 0; mi < 4; ++mi)
        #pragma unroll
        for (int ni = 0; ni < 4; ++ni)
            acc[mi][ni] = zz;

    auto stage = [&](int k0) {
        #pragma unroll
        for (int j = 0; j < 4; ++j) {
            __builtin_amdgcn_global_load_lds(
                (glob_void*)(pa + (size_t)j * 32 * GK + k0),
                (lds_void*)&As[(wv * 64 + 256 * j) * 8], 16, 0, 0);
            __builtin_amdgcn_global_load_lds(
                (glob_void*)(pb + (size_t)j * 32 * GK + k0),
                (lds_void*)&Bs[(wv * 64 + 256 * j) * 8], 16, 0, 0);
        }
    };

    stage(0);
    #pragma unroll 1
    for (int it = 0; it < NIT; ++it) {
        __syncthreads();   // staging of tile `it` complete

        short8 af[2][4], bfr[2][4];
        #pragma unroll
        for (int kk = 0; kk < 2; ++kk) {
            #pragma unroll
            for (int mi = 0; mi < 4; ++mi)
                af[kk][mi] = *(const short8*)
                    &As[((wm + mi * 16 + rr) * 8 + ((kk * 4 + kc) ^ (rr & 7))) * 8];
            #pragma unroll
            for (int ni = 0; ni < 4; ++ni)
                bfr[kk][ni] = *(const short8*)
                    &Bs[((wn + ni * 16 + rr) * 8 + ((kk * 4 + kc) ^ (rr & 7))) * 8];
        }
        __syncthreads();   // all waves done reading -> LDS free for restage

        if (it + 1 < NIT) stage((it + 1) * BK);   // hides under MFMAs below

        #pragma unroll
        for (int kk = 0; kk < 2; ++kk)
            #pragma unroll
            for (int mi = 0; mi < 4; ++mi)
                #pragma unroll
                for (int ni = 0; ni < 4; ++ni)
                    acc[mi][ni] = __builtin_amdgcn_mfma_f32_16x16x32_bf16(
                        af[kk][mi], bfr[kk][ni], acc[mi][ni], 0, 0, 0);
    }

    float bv[4];
    #pragma unroll
    for (int ni = 0; ni < 4; ++ni)
        bv[ni] = bias[nb * 128 + wn + ni * 16 + rr];

    // C/D layout: row-in-16 = kc*4 + reg, col-in-16 = rr (verified R1)
    #pragma unroll
    for (int mi = 0; mi < 4; ++mi) {
        #pragma unroll
        for (int ni = 0; ni < 4; ++ni) {
            const int col = nb * 128 + wn + ni * 16 + rr;
            #pragma unroll
            for (int r = 0; r < 4; ++r) {
                const int row = mb * 128 + wm + mi * 16 + kc * 4 + r;
                C[(size_t)row * GN + col] = acc[mi][ni][r] + bv[ni];
            }
        }
    }
}

extern "C" void kernel_launch(void* const* d_in, const int* in_sizes, int n_in,
                              void* d_out, int out_size, void* d_ws, size_t ws_size,
                              hipStream_t stream)
{
    (void)in_sizes; (void)n_in; (void)out_size; (void)ws_size;
    const float* x     = (const float*)d_in[0];
    const float* w     = (const float*)d_in[1];
    const float* bias  = (const float*)d_in[2];
    const float* mats  = (const float*)d_in[3];
    const int*   perms = (const int*)d_in[4];
    float* out = (float*)d_out;

    // ws: x hi-plane (64 MiB, becomes xq bf16 in place) | w hi-plane (32 MiB
    // -> wq) | mm. d_out doubles as lo-plane scratch (96 MiB <= 128 MiB),
    // fully overwritten by the GEMM afterwards (same-stream ordering).
    char* ws = (char*)d_ws;
    ushortT*  xq = (ushortT*)ws;
    ushortT*  wq = xq + (size_t)GM * GK;
    unsigned* mm = (unsigned*)(wq + (size_t)GN * GK);
    ushortT*  xlo = (ushortT*)out;
    ushortT*  wlo = xlo + (size_t)GM * GK;

    init_mm_kernel<<<1, 64, 0, stream>>>(mm);
    rotate_store_kernel<<<GM / 4, 256, 0, stream>>>(x, perms, mats, mm + 0, xq, xlo);
    rotate_store_kernel<<<GN / 4, 256, 0, stream>>>(w, perms, mats, mm + 2, wq, wlo);
    quant_kernel<<<(GM + GN) * (GK / 8) / 256, 256, 0, stream>>>(
        xq, xlo, mm, (unsigned)((size_t)GM * GK / 8));
    gemm_bias_kernel<<<GM / 128 * GN / 128, 256, 0, stream>>>(xq, wq, bias, out);
}